// Round 1
// baseline (331.293 us; speedup 1.0000x reference)
//
#include <hip/hip_runtime.h>

// LIF scan: mem = 0.25*mem + x[t]; spk = (mem >= 1); mem -= spk.
// x: [T=100, 32, 16384] f32. Parallel over N=524288 neurons, sequential in T.
// Memory-bound: 420 MB kernel traffic, floor ~67us @ 6.4 TB/s.
//
// History: R1 float4/8w/4deep=338 | R3 float2/16w/10deep=334 | R4 float1/32w=345
// | R5 +nontemporal=328.3. Kernel est. ~105us (~4 TB/s).
// R6 theory: all prior variants share a serial load->compute->load chunk shape:
// while a chunk is computed+stored, ZERO loads are outstanding (compiler won't
// hoist the next chunk's loads across 10 nt-stores + loop back-edge). Per-wave
// dead windows ~= compute+store phase length; aggregate read-request rate sags
// to ~2/3 of bus capability. Fix: two-buffer software pipeline — issue chunk
// c+1's loads BEFORE computing chunk c, so 10 loads stay in flight through
// every compute phase (s_waitcnt vmcnt(10) instead of vmcnt(0)).

constexpr int T = 100;
constexpr int N = 32 * 16384;      // 524288 neurons
constexpr int NV2 = N / 2;         // 262144 float2 columns
constexpr int CH = 10;             // loads in flight per buffer; T = 10 chunks

typedef float v2f __attribute__((ext_vector_type(2)));  // builtin-compatible float2

__device__ __forceinline__ void lif_steps(v2f& mem, const v2f* xs, v2f* __restrict__ op,
                                          int c) {
#pragma unroll
    for (int k = 0; k < CH; ++k) {
        const v2f xt = xs[k];
        v2f s;
        // __fmul_rn/__fadd_rn: match numpy's separate mul+add bit-exactly
        // (no FMA contraction) — hard threshold makes ulp drift cascade.
        mem.x = __fadd_rn(__fmul_rn(0.25f, mem.x), xt.x);
        mem.y = __fadd_rn(__fmul_rn(0.25f, mem.y), xt.y);
        s.x = (mem.x >= 1.0f) ? 1.0f : 0.0f;
        s.y = (mem.y >= 1.0f) ? 1.0f : 0.0f;
        mem.x -= s.x;
        mem.y -= s.y;
        __builtin_nontemporal_store(s, op + (size_t)(c + k) * NV2);
    }
}

__global__ __launch_bounds__(256) void lif_kernel(const v2f* __restrict__ x,
                                                  v2f* __restrict__ out) {
    const int i = blockIdx.x * 256 + threadIdx.x;   // float2 column index
    const v2f* xp = x + i;
    v2f* op = out + i;

    v2f mem = {0.f, 0.f};
    v2f xa[CH], xb[CH];

    // Prologue: fill buffer A with chunk 0.
#pragma unroll
    for (int k = 0; k < CH; ++k)
        xa[k] = __builtin_nontemporal_load(xp + (size_t)k * NV2);

    // Steady state: 5 iterations of (load B | compute A) then (load A | compute B).
    for (int c = 0; c < T; c += 2 * CH) {
        // Issue chunk c+CH loads BEFORE touching xa -> 10 loads in flight
        // while chunk c is computed+stored.
#pragma unroll
        for (int k = 0; k < CH; ++k)
            xb[k] = __builtin_nontemporal_load(xp + (size_t)(c + CH + k) * NV2);

        lif_steps(mem, xa, op, c);

        // Issue chunk c+2*CH (if any) before computing xb.
        if (c + 2 * CH < T) {
#pragma unroll
            for (int k = 0; k < CH; ++k)
                xa[k] = __builtin_nontemporal_load(xp + (size_t)(c + 2 * CH + k) * NV2);
        }

        lif_steps(mem, xb, op, c + CH);
    }
}

extern "C" void kernel_launch(void* const* d_in, const int* in_sizes, int n_in,
                              void* d_out, int out_size, void* d_ws, size_t ws_size,
                              hipStream_t stream) {
    const v2f* x = (const v2f*)d_in[0];
    v2f* out = (v2f*)d_out;
    const int blocks = NV2 / 256;   // 1024 -> 4 blocks/CU, 16 waves/CU
    lif_kernel<<<blocks, 256, 0, stream>>>(x, out);
}